// Round 1
// baseline (776.947 us; speedup 1.0000x reference)
//
#include <hip/hip_runtime.h>

#define N_NODES 100000
#define N_EDGES 2500000
#define DIM 32
#define N_REL 6
#define N_BASES 4
#define N_SEG (N_NODES * N_REL)          // 600000 (dst,rel) segments
#define RI 224                            // 6*32 relation means + 32 self (root)
#define RI_PAD 228                        // LDS row stride: 228/4=57 odd -> conflict-free b128
#define SCAN_TILE 1024
#define NB_SCAN ((N_SEG + SCAN_TILE - 1) / SCAN_TILE)   // 586

// ---------------- CSR build (once per call, reused by both layers) -------------
__global__ void hist_kernel(const int* __restrict__ dst, const int* __restrict__ et,
                            int* __restrict__ cnt) {
  int e = blockIdx.x * blockDim.x + threadIdx.x;
  if (e < N_EDGES) atomicAdd(&cnt[dst[e] * N_REL + et[e]], 1);
}

__global__ void scan_part_kernel(const int* __restrict__ cnt, int* __restrict__ offs,
                                 int* __restrict__ partial) {
  __shared__ int tsum[256];
  int t = threadIdx.x;
  int base = blockIdx.x * SCAN_TILE + t * 4;
  int v[4]; int s = 0;
#pragma unroll
  for (int k = 0; k < 4; ++k) {
    int idx = base + k;
    int c = (idx < N_SEG) ? cnt[idx] : 0;
    v[k] = s; s += c;
  }
  tsum[t] = s;
  __syncthreads();
  for (int off = 1; off < 256; off <<= 1) {
    int val = (t >= off) ? tsum[t - off] : 0;
    __syncthreads();
    tsum[t] += val;
    __syncthreads();
  }
  int excl = (t == 0) ? 0 : tsum[t - 1];
#pragma unroll
  for (int k = 0; k < 4; ++k) {
    int idx = base + k;
    if (idx < N_SEG) offs[idx] = excl + v[k];
  }
  if (t == 255) partial[blockIdx.x] = tsum[255];
}

__global__ void scan_mid_kernel(int* __restrict__ partial) {
  __shared__ int sh[1024];
  int t = threadIdx.x;
  sh[t] = (t < NB_SCAN) ? partial[t] : 0;
  __syncthreads();
  for (int off = 1; off < 1024; off <<= 1) {
    int val = (t >= off) ? sh[t - off] : 0;
    __syncthreads();
    sh[t] += val;
    __syncthreads();
  }
  if (t < NB_SCAN) partial[t] = (t == 0) ? 0 : sh[t - 1];
}

__global__ void scan_add_kernel(int* __restrict__ offs, const int* __restrict__ partial,
                                int* __restrict__ cursor) {
  int t = threadIdx.x;
  int b = blockIdx.x;
  int add = partial[b];
  int base = b * SCAN_TILE + t * 4;
#pragma unroll
  for (int k = 0; k < 4; ++k) {
    int idx = base + k;
    if (idx < N_SEG) { int v = offs[idx] + add; offs[idx] = v; cursor[idx] = v; }
  }
  if (b == 0 && t == 0) offs[N_SEG] = N_EDGES;
}

__global__ void scatter_kernel(const int* __restrict__ src, const int* __restrict__ dst,
                               const int* __restrict__ et, int* __restrict__ cursor,
                               int* __restrict__ sorted_src) {
  int e = blockIdx.x * blockDim.x + threadIdx.x;
  if (e < N_EDGES) {
    int s = dst[e] * N_REL + et[e];
    int pos = atomicAdd(&cursor[s], 1);
    sorted_src[pos] = src[e];
  }
}

// ------------- weights: Wt[o][ri] (transposed, padded), both layers ------------
__global__ void weights_kernel(const float* __restrict__ comp1, const float* __restrict__ basis1,
                               const float* __restrict__ root1,
                               const float* __restrict__ comp2, const float* __restrict__ basis2,
                               const float* __restrict__ root2,
                               float* __restrict__ Wt1, float* __restrict__ Wt2) {
  int idx = blockIdx.x * blockDim.x + threadIdx.x;
  if (idx >= 2 * DIM * RI) return;
  int layer = idx / (DIM * RI);
  int rem = idx - layer * (DIM * RI);
  int o = rem / RI;
  int ri = rem - o * RI;
  const float* comp  = layer ? comp2  : comp1;
  const float* basis = layer ? basis2 : basis1;
  const float* root  = layer ? root2  : root1;
  float val;
  if (ri < N_REL * DIM) {
    int r = ri >> 5, i = ri & 31;
    val = 0.f;
#pragma unroll
    for (int b = 0; b < N_BASES; ++b)
      val += comp[r * N_BASES + b] * basis[(b * DIM + i) * DIM + o];
  } else {
    int i = ri - N_REL * DIM;
    val = root[i * DIM + o];
  }
  (layer ? Wt2 : Wt1)[o * RI_PAD + ri] = val;
}

// ------------- aggregation: M[n][0..223] = 6 per-rel means || x[n] -------------
__global__ __launch_bounds__(256) void agg_kernel(const float* __restrict__ x,
                                                  const int* __restrict__ offs,
                                                  const int* __restrict__ sorted_src,
                                                  float* __restrict__ M) {
  int grp = threadIdx.x >> 5;
  int lane = threadIdx.x & 31;
  int n = blockIdx.x * 8 + grp;          // grid is exact: 12500*8 = 100000
  int base = n * N_REL;
  int p = offs[base];
  float* mrow = &M[(size_t)n * RI];
#pragma unroll
  for (int r = 0; r < N_REL; ++r) {
    int pend = offs[base + r + 1];
    int c = pend - p;
    float acc = 0.f;
    for (; p < pend; ++p) {
      int s = sorted_src[p];             // broadcast load
      acc += x[s * DIM + lane];          // 128B coalesced gather per group
    }
    mrow[r * DIM + lane] = (c > 0) ? acc / (float)c : 0.f;
  }
  mrow[N_REL * DIM + lane] = x[n * DIM + lane];   // self row for root term
}

// ------------- transform: y = M @ Wfull + bias (+ReLU) ------------------------
template <bool RELU>
__global__ __launch_bounds__(256) void trans_kernel(const float* __restrict__ M,
                                                    const float* __restrict__ Wt,
                                                    const float* __restrict__ bias,
                                                    float* __restrict__ y) {
  __shared__ float Wl[DIM * RI_PAD];     // 29184 B
  for (int j = threadIdx.x; j < DIM * RI_PAD; j += 256) Wl[j] = Wt[j];
  __syncthreads();
  int grp = threadIdx.x >> 5;            // 0..7 -> 4 nodes each; block = 32 nodes
  int lane = threadIdx.x & 31;           // output dim o
  int n0 = blockIdx.x * 32 + grp * 4;    // grid exact: 3125*32 = 100000
  float bv = bias[lane];
  float acc0 = bv, acc1 = bv, acc2 = bv, acc3 = bv;
  const float4* m0 = (const float4*)&M[(size_t)(n0 + 0) * RI];
  const float4* m1 = (const float4*)&M[(size_t)(n0 + 1) * RI];
  const float4* m2 = (const float4*)&M[(size_t)(n0 + 2) * RI];
  const float4* m3 = (const float4*)&M[(size_t)(n0 + 3) * RI];
  const float4* wrow = (const float4*)&Wl[lane * RI_PAD];
#pragma unroll 2
  for (int c = 0; c < RI / 4; ++c) {
    float4 w = wrow[c];                  // ds_read_b128, conflict-free (stride 57 chunks)
    float4 a = m0[c], b1 = m1[c], d = m2[c], e = m3[c];   // broadcast float4 loads
    acc0 += a.x * w.x + a.y * w.y + a.z * w.z + a.w * w.w;
    acc1 += b1.x * w.x + b1.y * w.y + b1.z * w.z + b1.w * w.w;
    acc2 += d.x * w.x + d.y * w.y + d.z * w.z + d.w * w.w;
    acc3 += e.x * w.x + e.y * w.y + e.z * w.z + e.w * w.w;
  }
  if (RELU) {
    acc0 = fmaxf(acc0, 0.f); acc1 = fmaxf(acc1, 0.f);
    acc2 = fmaxf(acc2, 0.f); acc3 = fmaxf(acc3, 0.f);
  }
  y[(n0 + 0) * DIM + lane] = acc0;
  y[(n0 + 1) * DIM + lane] = acc1;
  y[(n0 + 2) * DIM + lane] = acc2;
  y[(n0 + 3) * DIM + lane] = acc3;
}

extern "C" void kernel_launch(void* const* d_in, const int* in_sizes, int n_in,
                              void* d_out, int out_size, void* d_ws, size_t ws_size,
                              hipStream_t stream) {
  const float* embedding = (const float*)d_in[0];
  const int*   ei        = (const int*)d_in[1];     // [2, E]: src row, dst row
  const int*   et        = (const int*)d_in[2];
  const float* comp1  = (const float*)d_in[3];
  const float* basis1 = (const float*)d_in[4];
  const float* root1  = (const float*)d_in[5];
  const float* bias1  = (const float*)d_in[6];
  const float* comp2  = (const float*)d_in[7];
  const float* basis2 = (const float*)d_in[8];
  const float* root2  = (const float*)d_in[9];
  const float* bias2  = (const float*)d_in[10];
  float* out = (float*)d_out;

  const int* src = ei;
  const int* dst = ei + N_EDGES;

  // workspace layout (float units); total ~120 MB
  float* ws = (float*)d_ws;
  size_t o = 0;
  float* Wt1 = ws + o; o += DIM * RI_PAD;
  float* Wt2 = ws + o; o += DIM * RI_PAD;
  float* x1  = ws + o; o += (size_t)N_NODES * DIM;
  float* M   = ws + o; o += (size_t)N_NODES * RI;
  int* cnt        = (int*)(ws + o); o += N_SEG;
  int* offs       = (int*)(ws + o); o += N_SEG + 1;
  o = (o + 3) & ~(size_t)3;
  int* cursor     = (int*)(ws + o); o += N_SEG;
  int* sorted_src = (int*)(ws + o); o += N_EDGES;
  int* partial    = (int*)(ws + o); o += NB_SCAN;

  hipMemsetAsync(cnt, 0, N_SEG * sizeof(int), stream);
  int eb = (N_EDGES + 255) / 256;
  hist_kernel<<<eb, 256, 0, stream>>>(dst, et, cnt);
  scan_part_kernel<<<NB_SCAN, 256, 0, stream>>>(cnt, offs, partial);
  scan_mid_kernel<<<1, 1024, 0, stream>>>(partial);
  scan_add_kernel<<<NB_SCAN, 256, 0, stream>>>(offs, partial, cursor);
  scatter_kernel<<<eb, 256, 0, stream>>>(src, dst, et, cursor, sorted_src);
  weights_kernel<<<(2 * DIM * RI + 255) / 256, 256, 0, stream>>>(
      comp1, basis1, root1, comp2, basis2, root2, Wt1, Wt2);

  // layer 1
  agg_kernel<<<N_NODES / 8, 256, 0, stream>>>(embedding, offs, sorted_src, M);
  trans_kernel<true><<<N_NODES / 32, 256, 0, stream>>>(M, Wt1, bias1, x1);
  // layer 2
  agg_kernel<<<N_NODES / 8, 256, 0, stream>>>(x1, offs, sorted_src, M);
  trans_kernel<false><<<N_NODES / 32, 256, 0, stream>>>(M, Wt2, bias2, out);
}

// Round 2
// 654.127 us; speedup vs baseline: 1.1878x; 1.1878x over previous
//
#include <hip/hip_runtime.h>

#define N_NODES 100000
#define N_EDGES 2500000
#define DIM 32
#define N_REL 6
#define N_BASES 4
#define N_SEG (N_NODES * N_REL)           // 600000 (dst,rel) segments
#define RI 224                             // 6*32 relation means + 32 self (root)
#define RI_PAD 228                         // Wt row stride (floats); b128 4-way floor
#define NBUK 3125                          // dst>>5 buckets; 100000 = 3125*32 exactly
#define LSEG (32 * N_REL)                  // 192 local segments per bucket

// ---------------- bucket histogram (LDS-staged) -------------------------------
__global__ __launch_bounds__(1024) void bhist_kernel(const int* __restrict__ dst,
                                                     int* __restrict__ bcnt) {
  __shared__ int h[NBUK];
  for (int i = threadIdx.x; i < NBUK; i += 1024) h[i] = 0;
  __syncthreads();
  int stride = gridDim.x * 1024;
  for (int e = blockIdx.x * 1024 + threadIdx.x; e < N_EDGES; e += stride)
    atomicAdd(&h[dst[e] >> 5], 1);
  __syncthreads();
  for (int i = threadIdx.x; i < NBUK; i += 1024)
    if (h[i]) atomicAdd(&bcnt[i], h[i]);
}

// ---------------- bucket scan (single block) ----------------------------------
__global__ __launch_bounds__(1024) void bscan_kernel(const int* __restrict__ bcnt,
                                                     int* __restrict__ bOffs,
                                                     int* __restrict__ cursorA) {
  __shared__ int ts[1024];
  int t = threadIdx.x;
  int base = t * 4;
  int v[4]; int s = 0;
#pragma unroll
  for (int k = 0; k < 4; ++k) {
    int idx = base + k;
    int c = (idx < NBUK) ? bcnt[idx] : 0;
    v[k] = s; s += c;
  }
  ts[t] = s;
  __syncthreads();
  for (int off = 1; off < 1024; off <<= 1) {
    int u = (t >= off) ? ts[t - off] : 0;
    __syncthreads();
    ts[t] += u;
    __syncthreads();
  }
  int excl = (t == 0) ? 0 : ts[t - 1];
#pragma unroll
  for (int k = 0; k < 4; ++k) {
    int idx = base + k;
    if (idx < NBUK) { int o = excl + v[k]; bOffs[idx] = o; cursorA[idx] = o; }
  }
  if (t == 1023) bOffs[NBUK] = N_EDGES;
}

// ---------------- phase A: scatter packed payload into bucket regions ---------
__global__ void phaseA_kernel(const int* __restrict__ src, const int* __restrict__ dst,
                              const int* __restrict__ et, int* __restrict__ cursorA,
                              unsigned* __restrict__ packed) {
  int e = blockIdx.x * blockDim.x + threadIdx.x;
  if (e < N_EDGES) {
    int d = dst[e];
    int b = d >> 5;
    unsigned pl = ((unsigned)src[e] << 8) | ((unsigned)(d & 31) << 3) | (unsigned)et[e];
    int pos = atomicAdd(&cursorA[b], 1);   // sequential within bucket -> dense lines
    packed[pos] = pl;
  }
}

// ---------------- phase B: per-bucket local sort + CSR offsets ----------------
__global__ __launch_bounds__(256) void phaseB_kernel(const unsigned* __restrict__ packed,
                                                     const int* __restrict__ bOffs,
                                                     int* __restrict__ offs,
                                                     int* __restrict__ ssrc) {
  __shared__ int scnt[LSEG];
  __shared__ int sexcl[LSEG];
  __shared__ int ssc[256];
  int b = blockIdx.x;
  int t = threadIdx.x;
  int beg = bOffs[b], end = bOffs[b + 1];
  if (t < LSEG) scnt[t] = 0;
  __syncthreads();
  for (int i = beg + t; i < end; i += 256) {
    unsigned pl = packed[i];
    unsigned low = pl & 255u;
    int ls = (int)(low >> 3) * N_REL + (int)(low & 7u);
    atomicAdd(&scnt[ls], 1);
  }
  __syncthreads();
  int v = (t < LSEG) ? scnt[t] : 0;
  ssc[t] = v;
  __syncthreads();
  for (int off = 1; off < 256; off <<= 1) {
    int u = (t >= off) ? ssc[t - off] : 0;
    __syncthreads();
    ssc[t] += u;
    __syncthreads();
  }
  int excl = (t == 0) ? 0 : ssc[t - 1];
  if (t < LSEG) {
    sexcl[t] = excl;
    offs[b * LSEG + t] = beg + excl;     // global CSR offsets: bucket-major order
    scnt[t] = 0;
  }
  if (b == 0 && t == 0) offs[N_SEG] = N_EDGES;
  __syncthreads();
  for (int i = beg + t; i < end; i += 256) {
    unsigned pl = packed[i];
    unsigned low = pl & 255u;
    int ls = (int)(low >> 3) * N_REL + (int)(low & 7u);
    int lp = sexcl[ls] + atomicAdd(&scnt[ls], 1);
    ssrc[beg + lp] = (int)(pl >> 8);     // writes stay within ~3.2KB bucket region
  }
}

// ------------- weights: Wt[o][ri] (transposed, padded), both layers ------------
__global__ void weights_kernel(const float* __restrict__ comp1, const float* __restrict__ basis1,
                               const float* __restrict__ root1,
                               const float* __restrict__ comp2, const float* __restrict__ basis2,
                               const float* __restrict__ root2,
                               float* __restrict__ Wt1, float* __restrict__ Wt2) {
  int idx = blockIdx.x * blockDim.x + threadIdx.x;
  if (idx >= 2 * DIM * RI) return;
  int layer = idx / (DIM * RI);
  int rem = idx - layer * (DIM * RI);
  int o = rem / RI;
  int ri = rem - o * RI;
  const float* comp  = layer ? comp2  : comp1;
  const float* basis = layer ? basis2 : basis1;
  const float* root  = layer ? root2  : root1;
  float val;
  if (ri < N_REL * DIM) {
    int r = ri >> 5, i = ri & 31;
    val = 0.f;
#pragma unroll
    for (int bb = 0; bb < N_BASES; ++bb)
      val += comp[r * N_BASES + bb] * basis[(bb * DIM + i) * DIM + o];
  } else {
    int i = ri - N_REL * DIM;
    val = root[i * DIM + o];
  }
  (layer ? Wt2 : Wt1)[o * RI_PAD + ri] = val;
}

// ------------- fused layer: per-rel means -> LDS -> dot with W ----------------
template <bool RELU>
__global__ __launch_bounds__(1024) void layer_kernel(const float* __restrict__ x,
                                                     const int* __restrict__ offs,
                                                     const int* __restrict__ ssrc,
                                                     const float* __restrict__ Wt,
                                                     const float* __restrict__ bias,
                                                     float* __restrict__ y) {
  __shared__ float Wl[DIM * RI_PAD];     // 29184 B
  __shared__ float mbuf[32][RI];         // 28672 B; total 57856 B -> 2 blocks/CU
  for (int j = threadIdx.x; j < DIM * RI_PAD; j += 1024) Wl[j] = Wt[j];
  int grp = threadIdx.x >> 5;
  int lane = threadIdx.x & 31;
  int n = blockIdx.x * 32 + grp;         // grid exact: 3125*32 = 100000
  int base = n * N_REL;
  int p = offs[base];
  float* mrow = mbuf[grp];
#pragma unroll
  for (int r = 0; r < N_REL; ++r) {
    int pend = offs[base + r + 1];
    int c = pend - p;
    float acc = 0.f;
    for (; p < pend; ++p) {
      int s = ssrc[p];                   // broadcast load
      acc += x[s * DIM + lane];          // 128B coalesced gather per group (L2/L3)
    }
    mrow[r * DIM + lane] = (c > 0) ? acc / (float)c : 0.f;
  }
  mrow[N_REL * DIM + lane] = x[n * DIM + lane];
  __syncthreads();                       // covers Wl load + all groups' mbuf writes
  float accv = bias[lane];
  const float4* wrow = (const float4*)&Wl[lane * RI_PAD];
  const float4* mv = (const float4*)mrow;
#pragma unroll 4
  for (int c2 = 0; c2 < RI / 4; ++c2) {
    float4 w = wrow[c2];                 // b128, 4-way (floor) conflict
    float4 m = mv[c2];                   // same addr across lanes -> broadcast
    accv += m.x * w.x + m.y * w.y + m.z * w.z + m.w * w.w;
  }
  if (RELU) accv = fmaxf(accv, 0.f);
  y[n * DIM + lane] = accv;
}

extern "C" void kernel_launch(void* const* d_in, const int* in_sizes, int n_in,
                              void* d_out, int out_size, void* d_ws, size_t ws_size,
                              hipStream_t stream) {
  const float* embedding = (const float*)d_in[0];
  const int*   ei        = (const int*)d_in[1];     // [2, E]: src row, dst row
  const int*   et        = (const int*)d_in[2];
  const float* comp1  = (const float*)d_in[3];
  const float* basis1 = (const float*)d_in[4];
  const float* root1  = (const float*)d_in[5];
  const float* bias1  = (const float*)d_in[6];
  const float* comp2  = (const float*)d_in[7];
  const float* basis2 = (const float*)d_in[8];
  const float* root2  = (const float*)d_in[9];
  const float* bias2  = (const float*)d_in[10];
  float* out = (float*)d_out;

  const int* src = ei;
  const int* dst = ei + N_EDGES;

  float* ws = (float*)d_ws;
  size_t o = 0;
  float* Wt1 = ws + o; o += DIM * RI_PAD;
  float* Wt2 = ws + o; o += DIM * RI_PAD;
  float* x1  = ws + o; o += (size_t)N_NODES * DIM;
  int* bcnt       = (int*)(ws + o); o += NBUK;
  int* bOffs      = (int*)(ws + o); o += NBUK + 1;
  int* cursorA    = (int*)(ws + o); o += NBUK;
  int* offs       = (int*)(ws + o); o += N_SEG + 1;
  unsigned* packed = (unsigned*)(ws + o); o += N_EDGES;
  int* ssrc       = (int*)(ws + o); o += N_EDGES;

  hipMemsetAsync(bcnt, 0, NBUK * sizeof(int), stream);
  bhist_kernel<<<240, 1024, 0, stream>>>(dst, bcnt);
  bscan_kernel<<<1, 1024, 0, stream>>>(bcnt, bOffs, cursorA);
  phaseA_kernel<<<(N_EDGES + 255) / 256, 256, 0, stream>>>(src, dst, et, cursorA, packed);
  phaseB_kernel<<<NBUK, 256, 0, stream>>>(packed, bOffs, offs, ssrc);
  weights_kernel<<<(2 * DIM * RI + 255) / 256, 256, 0, stream>>>(
      comp1, basis1, root1, comp2, basis2, root2, Wt1, Wt2);

  layer_kernel<true><<<NBUK, 1024, 0, stream>>>(embedding, offs, ssrc, Wt1, bias1, x1);
  layer_kernel<false><<<NBUK, 1024, 0, stream>>>(x1, offs, ssrc, Wt2, bias2, out);
}

// Round 3
// 564.828 us; speedup vs baseline: 1.3755x; 1.1581x over previous
//
#include <hip/hip_runtime.h>

#define N_NODES 100000
#define N_EDGES 2500000
#define DIM 32
#define N_REL 6
#define N_BASES 4
#define N_SEG (N_NODES * N_REL)           // 600000 (dst,rel) segments
#define RI 224                             // 6*32 relation means + 32 self (root)
#define RI_PAD 228                         // Wt row stride (floats)
#define CB 196                             // coarse buckets: dst>>9 (512 nodes each; last=160)
#define CNODES 512
#define CSEG (CNODES * N_REL)              // 3072 fine segments per coarse bucket
#define CAP 72                             // LDS staging capacity per bucket (entries)
#define FLUSH 64                           // flush quantum (256 B)
#define PA_BLOCKS 128
#define LAYER_BLOCKS 3125                  // 32 nodes per block

// ---------------- coarse histogram -------------------------------------------
__global__ __launch_bounds__(1024) void bhist_kernel(const int* __restrict__ dst,
                                                     int* __restrict__ bcnt) {
  __shared__ int h[CB];
  for (int i = threadIdx.x; i < CB; i += 1024) h[i] = 0;
  __syncthreads();
  int stride = gridDim.x * 1024;
  for (int e = blockIdx.x * 1024 + threadIdx.x; e < N_EDGES; e += stride)
    atomicAdd(&h[dst[e] >> 9], 1);
  __syncthreads();
  for (int i = threadIdx.x; i < CB; i += 1024)
    if (h[i]) atomicAdd(&bcnt[i], h[i]);
}

// ---------------- coarse scan (single block) ----------------------------------
__global__ __launch_bounds__(256) void bscan_kernel(const int* __restrict__ bcnt,
                                                    int* __restrict__ bOffs,
                                                    int* __restrict__ cursorA) {
  __shared__ int ts[256];
  int t = threadIdx.x;
  int v = (t < CB) ? bcnt[t] : 0;
  ts[t] = v;
  __syncthreads();
  for (int off = 1; off < 256; off <<= 1) {
    int u = (t >= off) ? ts[t - off] : 0;
    __syncthreads();
    ts[t] += u;
    __syncthreads();
  }
  int excl = ts[t] - v;
  if (t < CB) { bOffs[t] = excl; cursorA[t] = excl; }
  if (t == CB - 1) bOffs[CB] = N_EDGES;
}

// ------- phase A: LDS-chunked partition into coarse buckets (clean writes) ----
// payload: src(17b)<<12 | dst_low9<<3 | et(3b)
__global__ __launch_bounds__(1024) void phaseA_kernel(const int* __restrict__ src,
                                                      const int* __restrict__ dst,
                                                      const int* __restrict__ et,
                                                      int* __restrict__ cursorA,
                                                      unsigned* __restrict__ packed) {
  __shared__ unsigned stage[CB][CAP];      // 56448 B
  __shared__ int cnt[CB];
  for (int i = threadIdx.x; i < CB; i += 1024) cnt[i] = 0;
  __syncthreads();
  int per = (N_EDGES + PA_BLOCKS - 1) / PA_BLOCKS;
  int bstart = blockIdx.x * per;
  int bend = bstart + per; if (bend > N_EDGES) bend = N_EDGES;
  int wid = threadIdx.x >> 6;
  int lane = threadIdx.x & 63;
  for (int base = bstart; base < bend; base += 1024) {
    int e = base + threadIdx.x;
    int b = -1, pos = -1; unsigned pl = 0;
    if (e < bend) {
      int d = dst[e];
      b = d >> 9;
      pl = ((unsigned)src[e] << 12) | ((unsigned)(d & 511) << 3) | (unsigned)et[e];
      pos = atomicAdd(&cnt[b], 1);
      if (pos < CAP) stage[b][pos] = pl;
    }
    __syncthreads();
    // flush full 64-entry chunks (each bucket owned by exactly one wave)
    for (int bb = wid; bb < CB; bb += 16) {
      int c = cnt[bb]; if (c > CAP) c = CAP;
      int nflush = (c / FLUSH) * FLUSH;
      if (nflush > 0) {
        int g = 0;
        if (lane == 0) g = atomicAdd(&cursorA[bb], nflush);
        g = __shfl(g, 0);
        for (int k = lane; k < nflush; k += 64)
          packed[g + k] = stage[bb][k];          // 256 B contiguous wave-write
        int rem = c - nflush;                    // <= CAP-FLUSH = 8
        unsigned tmp = (lane < rem) ? stage[bb][nflush + lane] : 0u;
        if (lane < rem) stage[bb][lane] = tmp;   // disjoint regions, no hazard
        if (lane == 0) cnt[bb] = rem;
      }
    }
    // rare overflow: direct append (atomics only, no LDS state touched)
    if (pos >= CAP) {
      int g = atomicAdd(&cursorA[b], 1);
      packed[g] = pl;
    }
    __syncthreads();
  }
  // final tail flush (runs of <=72 entries, contiguous per wave)
  for (int bb = wid; bb < CB; bb += 16) {
    int c = cnt[bb]; if (c > CAP) c = CAP;
    if (c > 0) {
      int g = 0;
      if (lane == 0) g = atomicAdd(&cursorA[bb], c);
      g = __shfl(g, 0);
      for (int k = lane; k < c; k += 64)
        packed[g + k] = stage[bb][k];
    }
  }
}

// ------- phase B: per-coarse-bucket fine sort -> node-major CSR ---------------
__global__ __launch_bounds__(1024) void phaseB_kernel(const unsigned* __restrict__ packed,
                                                      const int* __restrict__ bOffs,
                                                      int* __restrict__ offs,
                                                      int* __restrict__ ssrc) {
  __shared__ int scnt[CSEG];     // 12 KB
  __shared__ int sexcl[CSEG];    // 12 KB
  __shared__ int ssc[1024];      // 4 KB
  int b = blockIdx.x;
  int t = threadIdx.x;
  int beg = bOffs[b], end = bOffs[b + 1];
  for (int i = t; i < CSEG; i += 1024) scnt[i] = 0;
  __syncthreads();
  for (int i = beg + t; i < end; i += 1024) {
    unsigned pl = packed[i];
    int ls = (int)((pl >> 3) & 511u) * N_REL + (int)(pl & 7u);
    atomicAdd(&scnt[ls], 1);
  }
  __syncthreads();
  int b3 = t * 3;                // 3072 = 1024*3
  int a0 = scnt[b3], a1 = scnt[b3 + 1], a2 = scnt[b3 + 2];
  int s = a0 + a1 + a2;
  ssc[t] = s;
  __syncthreads();
  for (int off = 1; off < 1024; off <<= 1) {
    int u = (t >= off) ? ssc[t - off] : 0;
    __syncthreads();
    ssc[t] += u;
    __syncthreads();
  }
  int excl = ssc[t] - s;
  sexcl[b3] = excl; sexcl[b3 + 1] = excl + a0; sexcl[b3 + 2] = excl + a0 + a1;
  // global CSR offsets (node-major: offs[n*6+r], n = b*512 + dl)
#pragma unroll
  for (int k = 0; k < 3; ++k) {
    int ls = b3 + k;
    int gseg = b * CSEG + ls;
    if (gseg < N_SEG) offs[gseg] = beg + sexcl[ls];
  }
  if (b == 0 && t == 0) offs[N_SEG] = N_EDGES;
  // reset counters, then scatter within L2-resident [beg,end) region
  __syncthreads();
  scnt[b3] = 0; scnt[b3 + 1] = 0; scnt[b3 + 2] = 0;
  __syncthreads();
  for (int i = beg + t; i < end; i += 1024) {
    unsigned pl = packed[i];
    int ls = (int)((pl >> 3) & 511u) * N_REL + (int)(pl & 7u);
    int p = atomicAdd(&scnt[ls], 1);
    ssrc[beg + sexcl[ls] + p] = (int)(pl >> 12);
  }
}

// ------------- weights: Wt[o][ri] (transposed, padded), both layers ------------
__global__ void weights_kernel(const float* __restrict__ comp1, const float* __restrict__ basis1,
                               const float* __restrict__ root1,
                               const float* __restrict__ comp2, const float* __restrict__ basis2,
                               const float* __restrict__ root2,
                               float* __restrict__ Wt1, float* __restrict__ Wt2) {
  int idx = blockIdx.x * blockDim.x + threadIdx.x;
  if (idx >= 2 * DIM * RI) return;
  int layer = idx / (DIM * RI);
  int rem = idx - layer * (DIM * RI);
  int o = rem / RI;
  int ri = rem - o * RI;
  const float* comp  = layer ? comp2  : comp1;
  const float* basis = layer ? basis2 : basis1;
  const float* root  = layer ? root2  : root1;
  float val;
  if (ri < N_REL * DIM) {
    int r = ri >> 5, i = ri & 31;
    val = 0.f;
#pragma unroll
    for (int bb = 0; bb < N_BASES; ++bb)
      val += comp[r * N_BASES + bb] * basis[(bb * DIM + i) * DIM + o];
  } else {
    int i = ri - N_REL * DIM;
    val = root[i * DIM + o];
  }
  (layer ? Wt2 : Wt1)[o * RI_PAD + ri] = val;
}

// ------------- fused layer: per-rel means -> LDS -> dot with W ----------------
template <bool RELU>
__global__ __launch_bounds__(1024) void layer_kernel(const float* __restrict__ x,
                                                     const int* __restrict__ offs,
                                                     const int* __restrict__ ssrc,
                                                     const float* __restrict__ Wt,
                                                     const float* __restrict__ bias,
                                                     float* __restrict__ y) {
  __shared__ float Wl[DIM * RI_PAD];     // 29184 B
  __shared__ float mbuf[32][RI];         // 28672 B
  for (int j = threadIdx.x; j < DIM * RI_PAD; j += 1024) Wl[j] = Wt[j];
  int grp = threadIdx.x >> 5;
  int lane = threadIdx.x & 31;
  int n = blockIdx.x * 32 + grp;
  int base = n * N_REL;
  int p = offs[base];
  float* mrow = mbuf[grp];
#pragma unroll
  for (int r = 0; r < N_REL; ++r) {
    int pend = offs[base + r + 1];
    int c = pend - p;
    float acc = 0.f;
    for (; p < pend; ++p) {
      int s = ssrc[p];
      acc += x[s * DIM + lane];
    }
    mrow[r * DIM + lane] = (c > 0) ? acc / (float)c : 0.f;
  }
  mrow[N_REL * DIM + lane] = x[n * DIM + lane];
  __syncthreads();
  float accv = bias[lane];
  const float4* wrow = (const float4*)&Wl[lane * RI_PAD];
  const float4* mv = (const float4*)mrow;
#pragma unroll 4
  for (int c2 = 0; c2 < RI / 4; ++c2) {
    float4 w = wrow[c2];
    float4 m = mv[c2];
    accv += m.x * w.x + m.y * w.y + m.z * w.z + m.w * w.w;
  }
  if (RELU) accv = fmaxf(accv, 0.f);
  y[n * DIM + lane] = accv;
}

extern "C" void kernel_launch(void* const* d_in, const int* in_sizes, int n_in,
                              void* d_out, int out_size, void* d_ws, size_t ws_size,
                              hipStream_t stream) {
  const float* embedding = (const float*)d_in[0];
  const int*   ei        = (const int*)d_in[1];     // [2, E]: src row, dst row
  const int*   et        = (const int*)d_in[2];
  const float* comp1  = (const float*)d_in[3];
  const float* basis1 = (const float*)d_in[4];
  const float* root1  = (const float*)d_in[5];
  const float* bias1  = (const float*)d_in[6];
  const float* comp2  = (const float*)d_in[7];
  const float* basis2 = (const float*)d_in[8];
  const float* root2  = (const float*)d_in[9];
  const float* bias2  = (const float*)d_in[10];
  float* out = (float*)d_out;

  const int* src = ei;
  const int* dst = ei + N_EDGES;

  float* ws = (float*)d_ws;
  size_t o = 0;
  float* Wt1 = ws + o; o += DIM * RI_PAD;
  float* Wt2 = ws + o; o += DIM * RI_PAD;
  float* x1  = ws + o; o += (size_t)N_NODES * DIM;
  int* bcnt       = (int*)(ws + o); o += CB;
  int* bOffs      = (int*)(ws + o); o += CB + 1;
  int* cursorA    = (int*)(ws + o); o += CB;
  int* offs       = (int*)(ws + o); o += N_SEG + 1;
  unsigned* packed = (unsigned*)(ws + o); o += N_EDGES;
  int* ssrc       = (int*)(ws + o); o += N_EDGES;

  hipMemsetAsync(bcnt, 0, CB * sizeof(int), stream);
  bhist_kernel<<<240, 1024, 0, stream>>>(dst, bcnt);
  bscan_kernel<<<1, 256, 0, stream>>>(bcnt, bOffs, cursorA);
  phaseA_kernel<<<PA_BLOCKS, 1024, 0, stream>>>(src, dst, et, cursorA, packed);
  phaseB_kernel<<<CB, 1024, 0, stream>>>(packed, bOffs, offs, ssrc);
  weights_kernel<<<(2 * DIM * RI + 255) / 256, 256, 0, stream>>>(
      comp1, basis1, root1, comp2, basis2, root2, Wt1, Wt2);

  layer_kernel<true><<<LAYER_BLOCKS, 1024, 0, stream>>>(embedding, offs, ssrc, Wt1, bias1, x1);
  layer_kernel<false><<<LAYER_BLOCKS, 1024, 0, stream>>>(x1, offs, ssrc, Wt2, bias2, out);
}

// Round 4
// 468.535 us; speedup vs baseline: 1.6582x; 1.2055x over previous
//
#include <hip/hip_runtime.h>

#define N_NODES 100000
#define N_EDGES 2500000
#define DIM 32
#define N_REL 6
#define N_BASES 4
#define N_SEG (N_NODES * N_REL)           // 600000 (dst,rel) segments
#define RI 224                             // 6*32 relation means + 32 self (root)
#define RI_PAD 228                         // Wt row stride (floats)
#define CB 196                             // coarse buckets: dst>>9 (512 nodes each; last=160)
#define CNODES 512
#define CSEG (CNODES * N_REL)              // 3072 fine segments per coarse bucket
#define CAP 72                             // LDS staging capacity per bucket (entries)
#define FLUSH 64                           // flush quantum (256 B)
#define PA_BLOCKS 128
#define LAYER_BLOCKS 3125                  // 32 nodes per block

// ---------------- coarse histogram -------------------------------------------
__global__ __launch_bounds__(1024) void bhist_kernel(const int* __restrict__ dst,
                                                     int* __restrict__ bcnt) {
  __shared__ int h[CB];
  for (int i = threadIdx.x; i < CB; i += 1024) h[i] = 0;
  __syncthreads();
  int stride = gridDim.x * 1024;
  for (int e = blockIdx.x * 1024 + threadIdx.x; e < N_EDGES; e += stride)
    atomicAdd(&h[dst[e] >> 9], 1);
  __syncthreads();
  for (int i = threadIdx.x; i < CB; i += 1024)
    if (h[i]) atomicAdd(&bcnt[i], h[i]);
}

// ---------------- coarse scan (single block) ----------------------------------
__global__ __launch_bounds__(256) void bscan_kernel(const int* __restrict__ bcnt,
                                                    int* __restrict__ bOffs,
                                                    int* __restrict__ cursorA) {
  __shared__ int ts[256];
  int t = threadIdx.x;
  int v = (t < CB) ? bcnt[t] : 0;
  ts[t] = v;
  __syncthreads();
  for (int off = 1; off < 256; off <<= 1) {
    int u = (t >= off) ? ts[t - off] : 0;
    __syncthreads();
    ts[t] += u;
    __syncthreads();
  }
  int excl = ts[t] - v;
  if (t < CB) { bOffs[t] = excl; cursorA[t] = excl; }
  if (t == CB - 1) bOffs[CB] = N_EDGES;
}

// ------- phase A: LDS-chunked partition into coarse buckets (clean writes) ----
// payload: src(17b)<<12 | dst_low9<<3 | et(3b)
__global__ __launch_bounds__(1024) void phaseA_kernel(const int* __restrict__ src,
                                                      const int* __restrict__ dst,
                                                      const int* __restrict__ et,
                                                      int* __restrict__ cursorA,
                                                      unsigned* __restrict__ packed) {
  __shared__ unsigned stage[CB][CAP];      // 56448 B
  __shared__ int cnt[CB];
  for (int i = threadIdx.x; i < CB; i += 1024) cnt[i] = 0;
  __syncthreads();
  int per = (N_EDGES + PA_BLOCKS - 1) / PA_BLOCKS;
  int bstart = blockIdx.x * per;
  int bend = bstart + per; if (bend > N_EDGES) bend = N_EDGES;
  int wid = threadIdx.x >> 6;
  int lane = threadIdx.x & 63;
  for (int base = bstart; base < bend; base += 1024) {
    int e = base + threadIdx.x;
    int b = -1, pos = -1; unsigned pl = 0;
    if (e < bend) {
      int d = dst[e];
      b = d >> 9;
      pl = ((unsigned)src[e] << 12) | ((unsigned)(d & 511) << 3) | (unsigned)et[e];
      pos = atomicAdd(&cnt[b], 1);
      if (pos < CAP) stage[b][pos] = pl;
    }
    __syncthreads();
    // flush full 64-entry chunks (each bucket owned by exactly one wave)
    for (int bb = wid; bb < CB; bb += 16) {
      int c = cnt[bb]; if (c > CAP) c = CAP;
      int nflush = (c / FLUSH) * FLUSH;
      if (nflush > 0) {
        int g = 0;
        if (lane == 0) g = atomicAdd(&cursorA[bb], nflush);
        g = __shfl(g, 0);
        for (int k = lane; k < nflush; k += 64)
          packed[g + k] = stage[bb][k];          // 256 B contiguous wave-write
        int rem = c - nflush;                    // <= CAP-FLUSH = 8
        unsigned tmp = (lane < rem) ? stage[bb][nflush + lane] : 0u;
        if (lane < rem) stage[bb][lane] = tmp;   // disjoint regions, no hazard
        if (lane == 0) cnt[bb] = rem;
      }
    }
    // rare overflow: direct append (atomics only, no LDS state touched)
    if (pos >= CAP) {
      int g = atomicAdd(&cursorA[b], 1);
      packed[g] = pl;
    }
    __syncthreads();
  }
  // final tail flush (runs of <=72 entries, contiguous per wave)
  for (int bb = wid; bb < CB; bb += 16) {
    int c = cnt[bb]; if (c > CAP) c = CAP;
    if (c > 0) {
      int g = 0;
      if (lane == 0) g = atomicAdd(&cursorA[bb], c);
      g = __shfl(g, 0);
      for (int k = lane; k < c; k += 64)
        packed[g + k] = stage[bb][k];
    }
  }
}

// ------- phase B: per-coarse-bucket fine sort -> node-major CSR ---------------
__global__ __launch_bounds__(1024) void phaseB_kernel(const unsigned* __restrict__ packed,
                                                      const int* __restrict__ bOffs,
                                                      int* __restrict__ offs,
                                                      int* __restrict__ ssrc) {
  __shared__ int scnt[CSEG];     // 12 KB
  __shared__ int sexcl[CSEG];    // 12 KB
  __shared__ int ssc[1024];      // 4 KB
  int b = blockIdx.x;
  int t = threadIdx.x;
  int beg = bOffs[b], end = bOffs[b + 1];
  for (int i = t; i < CSEG; i += 1024) scnt[i] = 0;
  __syncthreads();
  for (int i = beg + t; i < end; i += 1024) {
    unsigned pl = packed[i];
    int ls = (int)((pl >> 3) & 511u) * N_REL + (int)(pl & 7u);
    atomicAdd(&scnt[ls], 1);
  }
  __syncthreads();
  int b3 = t * 3;                // 3072 = 1024*3
  int a0 = scnt[b3], a1 = scnt[b3 + 1], a2 = scnt[b3 + 2];
  int s = a0 + a1 + a2;
  ssc[t] = s;
  __syncthreads();
  for (int off = 1; off < 1024; off <<= 1) {
    int u = (t >= off) ? ssc[t - off] : 0;
    __syncthreads();
    ssc[t] += u;
    __syncthreads();
  }
  int excl = ssc[t] - s;
  sexcl[b3] = excl; sexcl[b3 + 1] = excl + a0; sexcl[b3 + 2] = excl + a0 + a1;
#pragma unroll
  for (int k = 0; k < 3; ++k) {
    int ls = b3 + k;
    int gseg = b * CSEG + ls;
    if (gseg < N_SEG) offs[gseg] = beg + sexcl[ls];
  }
  if (b == 0 && t == 0) offs[N_SEG] = N_EDGES;
  __syncthreads();
  scnt[b3] = 0; scnt[b3 + 1] = 0; scnt[b3 + 2] = 0;
  __syncthreads();
  for (int i = beg + t; i < end; i += 1024) {
    unsigned pl = packed[i];
    int ls = (int)((pl >> 3) & 511u) * N_REL + (int)(pl & 7u);
    int p = atomicAdd(&scnt[ls], 1);
    ssrc[beg + sexcl[ls] + p] = (int)(pl >> 12);
  }
}

// ------------- weights: Wt[o][ri] (transposed, padded), both layers ------------
__global__ void weights_kernel(const float* __restrict__ comp1, const float* __restrict__ basis1,
                               const float* __restrict__ root1,
                               const float* __restrict__ comp2, const float* __restrict__ basis2,
                               const float* __restrict__ root2,
                               float* __restrict__ Wt1, float* __restrict__ Wt2) {
  int idx = blockIdx.x * blockDim.x + threadIdx.x;
  if (idx >= 2 * DIM * RI) return;
  int layer = idx / (DIM * RI);
  int rem = idx - layer * (DIM * RI);
  int o = rem / RI;
  int ri = rem - o * RI;
  const float* comp  = layer ? comp2  : comp1;
  const float* basis = layer ? basis2 : basis1;
  const float* root  = layer ? root2  : root1;
  float val;
  if (ri < N_REL * DIM) {
    int r = ri >> 5, i = ri & 31;
    val = 0.f;
#pragma unroll
    for (int bb = 0; bb < N_BASES; ++bb)
      val += comp[r * N_BASES + bb] * basis[(bb * DIM + i) * DIM + o];
  } else {
    int i = ri - N_REL * DIM;
    val = root[i * DIM + o];
  }
  (layer ? Wt2 : Wt1)[o * RI_PAD + ri] = val;
}

// ------------- fused layer: flat deep-MLP gather -> means -> dot with W -------
template <bool RELU>
__global__ __launch_bounds__(1024) void layer_kernel(const float* __restrict__ x,
                                                     const int* __restrict__ offs,
                                                     const int* __restrict__ ssrc,
                                                     const float* __restrict__ Wt,
                                                     const float* __restrict__ bias,
                                                     float* __restrict__ y) {
  __shared__ float Wl[DIM * RI_PAD];     // 29184 B
  __shared__ float mbuf[32][RI];         // 28672 B
  for (int j = threadIdx.x; j < DIM * RI_PAD; j += 1024) Wl[j] = Wt[j];
  int grp = threadIdx.x >> 5;
  int lane = threadIdx.x & 31;
  int n = blockIdx.x * 32 + grp;
  int base = n * N_REL;
  // relation boundaries b0..b6 as named registers (7-lane coalesced load + shfl)
  int t7 = offs[base + ((lane < 7) ? lane : 0)];
  int b0 = __shfl(t7, 0, 32);
  int b1 = __shfl(t7, 1, 32);
  int b2 = __shfl(t7, 2, 32);
  int b3 = __shfl(t7, 3, 32);
  int b4 = __shfl(t7, 4, 32);
  int b5 = __shfl(t7, 5, 32);
  int b6 = __shfl(t7, 6, 32);
  // one-sided partial sums: A_k = sum over edges with p >= b_k
  float a0 = 0.f, a1 = 0.f, a2 = 0.f, a3 = 0.f, a4 = 0.f, a5 = 0.f;
  for (int chunk = b0; chunk < b6; chunk += 32) {
    int myp = chunk + lane;
    int sv = ssrc[(myp < b6) ? myp : (b6 - 1)];   // one coalesced load per 32 edges
    int m = b6 - chunk;                           // uniform within group
#pragma unroll
    for (int e = 0; e < 32; ++e) {
      if (e < m) {
        int se = __shfl(sv, e, 32);               // ds_bpermute, independent per e
        float v = x[(size_t)se * DIM + lane];     // 32 gathers in flight
        int pe = chunk + e;
        a0 += v;
        a1 += (pe >= b1) ? v : 0.f;
        a2 += (pe >= b2) ? v : 0.f;
        a3 += (pe >= b3) ? v : 0.f;
        a4 += (pe >= b4) ? v : 0.f;
        a5 += (pe >= b5) ? v : 0.f;
      }
    }
  }
  // per-relation sums S_r = A_r - A_{r+1}; means with zero-guard
  float s0 = a0 - a1, s1 = a1 - a2, s2 = a2 - a3, s3 = a3 - a4, s4 = a4 - a5, s5 = a5;
  int c0 = b1 - b0, c1 = b2 - b1, c2 = b3 - b2, c3 = b4 - b3, c4 = b5 - b4, c5 = b6 - b5;
  float* mrow = mbuf[grp];
  mrow[0 * DIM + lane] = c0 ? s0 / (float)c0 : 0.f;
  mrow[1 * DIM + lane] = c1 ? s1 / (float)c1 : 0.f;
  mrow[2 * DIM + lane] = c2 ? s2 / (float)c2 : 0.f;
  mrow[3 * DIM + lane] = c3 ? s3 / (float)c3 : 0.f;
  mrow[4 * DIM + lane] = c4 ? s4 / (float)c4 : 0.f;
  mrow[5 * DIM + lane] = c5 ? s5 / (float)c5 : 0.f;
  mrow[N_REL * DIM + lane] = x[n * DIM + lane];
  __syncthreads();
  float accv = bias[lane];
  const float4* wrow = (const float4*)&Wl[lane * RI_PAD];
  const float4* mv = (const float4*)mrow;
#pragma unroll 4
  for (int cc = 0; cc < RI / 4; ++cc) {
    float4 w = wrow[cc];
    float4 mm = mv[cc];
    accv += mm.x * w.x + mm.y * w.y + mm.z * w.z + mm.w * w.w;
  }
  if (RELU) accv = fmaxf(accv, 0.f);
  y[n * DIM + lane] = accv;
}

extern "C" void kernel_launch(void* const* d_in, const int* in_sizes, int n_in,
                              void* d_out, int out_size, void* d_ws, size_t ws_size,
                              hipStream_t stream) {
  const float* embedding = (const float*)d_in[0];
  const int*   ei        = (const int*)d_in[1];     // [2, E]: src row, dst row
  const int*   et        = (const int*)d_in[2];
  const float* comp1  = (const float*)d_in[3];
  const float* basis1 = (const float*)d_in[4];
  const float* root1  = (const float*)d_in[5];
  const float* bias1  = (const float*)d_in[6];
  const float* comp2  = (const float*)d_in[7];
  const float* basis2 = (const float*)d_in[8];
  const float* root2  = (const float*)d_in[9];
  const float* bias2  = (const float*)d_in[10];
  float* out = (float*)d_out;

  const int* src = ei;
  const int* dst = ei + N_EDGES;

  float* ws = (float*)d_ws;
  size_t o = 0;
  float* Wt1 = ws + o; o += DIM * RI_PAD;
  float* Wt2 = ws + o; o += DIM * RI_PAD;
  float* x1  = ws + o; o += (size_t)N_NODES * DIM;
  int* bcnt       = (int*)(ws + o); o += CB;
  int* bOffs      = (int*)(ws + o); o += CB + 1;
  int* cursorA    = (int*)(ws + o); o += CB;
  int* offs       = (int*)(ws + o); o += N_SEG + 1;
  unsigned* packed = (unsigned*)(ws + o); o += N_EDGES;
  int* ssrc       = (int*)(ws + o); o += N_EDGES;

  hipMemsetAsync(bcnt, 0, CB * sizeof(int), stream);
  bhist_kernel<<<240, 1024, 0, stream>>>(dst, bcnt);
  bscan_kernel<<<1, 256, 0, stream>>>(bcnt, bOffs, cursorA);
  phaseA_kernel<<<PA_BLOCKS, 1024, 0, stream>>>(src, dst, et, cursorA, packed);
  phaseB_kernel<<<CB, 1024, 0, stream>>>(packed, bOffs, offs, ssrc);
  weights_kernel<<<(2 * DIM * RI + 255) / 256, 256, 0, stream>>>(
      comp1, basis1, root1, comp2, basis2, root2, Wt1, Wt2);

  layer_kernel<true><<<LAYER_BLOCKS, 1024, 0, stream>>>(embedding, offs, ssrc, Wt1, bias1, x1);
  layer_kernel<false><<<LAYER_BLOCKS, 1024, 0, stream>>>(x1, offs, ssrc, Wt2, bias2, out);
}